// Round 1
// baseline (173.606 us; speedup 1.0000x reference)
//
#include <hip/hip_runtime.h>
#include <hip/hip_cooperative_groups.h>
#include <math.h>

namespace cg = cooperative_groups;

#define NB 8
#define NH 8
#define SEQ 512
#define DK 64
#define NC 5
#define D_IN 262144   // 8*512*64 per batch
#define OUT_SCORE (NB*NH*SEQ*SEQ)   // 16777216
#define PROJ_BLOCKS 128

typedef short short8 __attribute__((ext_vector_type(8)));
typedef float f32x16 __attribute__((ext_vector_type(16)));

// fp32 -> bf16 (RTNE), bit pattern in a short
__device__ __forceinline__ short f2bf(float f) {
  unsigned u = __float_as_uint(f);
  u += 0x7fffu + ((u >> 16) & 1u);
  return (short)(u >> 16);
}
__device__ __forceinline__ short8 pack8(float4 a, float4 b) {
  short8 r;
  r[0] = f2bf(a.x); r[1] = f2bf(a.y); r[2] = f2bf(a.z); r[3] = f2bf(a.w);
  r[4] = f2bf(b.x); r[5] = f2bf(b.y); r[6] = f2bf(b.z); r[7] = f2bf(b.w);
  return r;
}

// ------- Cooperative kernel: proj partials (all 128 blocks) -> grid.sync ->
// ------- block 0: parallel colsum + stats + loss + means. Replaces the old
// ------- proj_kernel + small_kernel pair (one launch, no 1-wave tail kernel).
__global__ __launch_bounds__(256) void proj_small_kernel(
    const float* __restrict__ K, const float* __restrict__ Wp,
    float* __restrict__ part, const float* __restrict__ bp,
    const float* __restrict__ Wq, const float* __restrict__ bq,
    const float* __restrict__ Wk, const float* __restrict__ bk,
    float* __restrict__ means, float* __restrict__ loss_out) {
  // ---------------- phase A: per-block partials of ck[b][c] ----------------
  const float4* Wp4 = (const float4*)Wp;
  float acc[NB][NC];
#pragma unroll
  for (int b = 0; b < NB; ++b)
#pragma unroll
    for (int c = 0; c < NC; ++c) acc[b][c] = 0.f;

#pragma unroll
  for (int it = 0; it < 2; ++it) {
    int i4 = blockIdx.x * 512 + it * 256 + threadIdx.x;  // float4 idx over D_IN
    float w[20];
#pragma unroll
    for (int t = 0; t < 5; ++t) {
      float4 v = Wp4[i4 * 5 + t];
      w[4*t+0] = v.x; w[4*t+1] = v.y; w[4*t+2] = v.z; w[4*t+3] = v.w;
    }
#pragma unroll
    for (int b = 0; b < NB; ++b) {
      float4 kv = ((const float4*)(K + (size_t)b * D_IN))[i4];
      float ke[4] = {kv.x, kv.y, kv.z, kv.w};
#pragma unroll
      for (int e = 0; e < 4; ++e)
#pragma unroll
        for (int c = 0; c < NC; ++c)
          acc[b][c] = fmaf(ke[e], w[5*e + c], acc[b][c]);
    }
  }

  __shared__ float red[4][NB * NC];
  {
    int wave = threadIdx.x >> 6;
    int lane = threadIdx.x & 63;
#pragma unroll
    for (int bc = 0; bc < NB * NC; ++bc) {
      float v = acc[bc / NC][bc % NC];
#pragma unroll
      for (int off = 32; off > 0; off >>= 1) v += __shfl_down(v, off);
      if (lane == 0) red[wave][bc] = v;
    }
    __syncthreads();
    if (threadIdx.x < NB * NC)
      part[blockIdx.x * (NB * NC) + threadIdx.x] =
          red[0][threadIdx.x] + red[1][threadIdx.x] +
          red[2][threadIdx.x] + red[3][threadIdx.x];
  }

  __threadfence();                 // make part[] visible device-wide
  cg::this_grid().sync();

  if (blockIdx.x != 0) return;

  // ---------------- phase B (block 0 only): reduce + stats + loss + means ---
  __shared__ float cs4[4][NB * NC];
  __shared__ float colsum[NB * NC];
  __shared__ float cq[NB][NC], ckk[NB][NC], ce_sh[NB];
  __shared__ int inds[NB];
  int t = threadIdx.x;

  // 160 threads x 32-wide unrolled slices: 32 independent loads in flight
  // per thread (old version: 1 thread per column, serial 128-deep chain).
  if (t < 160) {
    int sl = t / 40;
    int c  = t - sl * 40;
    float s = 0.f;
#pragma unroll
    for (int i = 0; i < 32; ++i) s += part[(sl * 32 + i) * (NB * NC) + c];
    cs4[sl][c] = s;
  }
  __syncthreads();
  if (t < NB * NC)
    colsum[t] = cs4[0][t] + cs4[1][t] + cs4[2][t] + cs4[3][t];
  __syncthreads();

  if (t < NB) {
    float cp[NC], zq[NC], zk[NC];
#pragma unroll
    for (int c = 0; c < NC; ++c) cp[c] = colsum[t * NC + c] + bp[c];
#pragma unroll
    for (int c = 0; c < NC; ++c) { zq[c] = bq[c]; zk[c] = bk[c]; }
#pragma unroll
    for (int j = 0; j < NC; ++j)
#pragma unroll
      for (int c = 0; c < NC; ++c) {
        zq[c] = fmaf(cp[j], Wq[j * NC + c], zq[c]);
        zk[c] = fmaf(cp[j], Wk[j * NC + c], zk[c]);
      }
    float m = zq[0];
#pragma unroll
    for (int c = 1; c < NC; ++c) m = fmaxf(m, zq[c]);
    float e[NC], s = 0.f;
#pragma unroll
    for (int c = 0; c < NC; ++c) { e[c] = expf(zq[c] - m); s += e[c]; }
    float inv = 1.f / s;
    float p[NC];
#pragma unroll
    for (int c = 0; c < NC; ++c) { p[c] = e[c] * inv; cq[t][c] = p[c]; }
    int am = 0; float bv = p[0];
#pragma unroll
    for (int c = 1; c < NC; ++c) if (p[c] > bv) { bv = p[c]; am = c; }
    inds[t] = am;
    float se = 0.f;
#pragma unroll
    for (int c = 0; c < NC; ++c) se += expf(p[c] - bv);
    float lse = bv + logf(se);
    float ceb = 0.f;
#pragma unroll
    for (int c = 0; c < NC; ++c) ceb -= p[c] * (p[c] - lse);
    ce_sh[t] = ceb;
    m = zk[0];
#pragma unroll
    for (int c = 1; c < NC; ++c) m = fmaxf(m, zk[c]);
    s = 0.f;
#pragma unroll
    for (int c = 0; c < NC; ++c) { e[c] = expf(zk[c] - m); s += e[c]; }
    inv = 1.f / s;
#pragma unroll
    for (int c = 0; c < NC; ++c) ckk[t][c] = e[c] * inv;
  }
  __syncthreads();
  if (t == 0) {
    float mu[NC];
#pragma unroll
    for (int c = 0; c < NC; ++c) {
      float sm = 0.f;
      for (int b = 0; b < NB; ++b) sm += cq[b][c];
      mu[c] = sm * 0.125f;
    }
    float loss_lp = 0.f;
#pragma unroll
    for (int c = 0; c < NC; ++c) {
      float sm = 0.f;
      for (int b = 0; b < NB; ++b) sm += ckk[b][c];
      float mk = sm * 0.125f;
      float var = 0.f;
      for (int b = 0; b < NB; ++b) {
        float d = ckk[b][c] - mk;
        var += d * d;
      }
      var *= (1.f / 7.f);                 // ddof=1
      float sd = sqrtf(var);
      float sigma = log1pf(expf(sd));     // softplus
      float ls = logf(sigma);
      for (int b = 0; b < NB; ++b) {
        float z = (ckk[b][c] - mu[c]) / sigma;
        loss_lp += -0.5f * z * z - ls - 0.91893853320467274f;
      }
    }
    float ce = 0.f;
    for (int b = 0; b < NB; ++b) ce += ce_sh[b];
    ce *= 0.125f;
    loss_out[0] = -(loss_lp / 40.f) + ce;
  }
  __syncthreads();
  // means[c][j] = (1/8) * sum_{b: inds[b] != c+1} K[b*D_IN + j],  j<512
  for (int idx = t; idx < NC * 512; idx += 256) {
    int c = idx >> 9, j = idx & 511;
    float sm = 0.f;
#pragma unroll
    for (int b = 0; b < NB; ++b)
      if (inds[b] != c + 1) sm += K[(size_t)b * D_IN + j];
    means[idx] = sm * 0.125f;
  }
}

// ---- Kernel C: 128q x 64k tiles, wave = 32q x 64k, 2048 blocks, 32 KB LDS ----
// -> 5 blocks/CU = 20 waves/CU. Output stores are NONTEMPORAL: 64 MB streaming
// writes otherwise evict the ~2 MB/XCD of Q/K tiles from L2 (out:L2 = 8 MB:4 MiB
// per XCD), forcing re-fetch above the 16 MB unique floor.
#define LDSTRIDE 72   // shorts; 144 B rows: 16B-aligned, uniform b128 bank spread
__global__ __launch_bounds__(256) void score_kernel(const float* __restrict__ Q,
                                                    const float* __restrict__ K,
                                                    const float* __restrict__ means,
                                                    float* __restrict__ out) {
  __shared__ short Qs[128 * LDSTRIDE];       // 18432 B
  __shared__ short Ks[64 * LDSTRIDE];        //  9216 B
  __shared__ float qcbuf[4 * 32 * 10];       //  5120 B  => 32768 B total

  const int bh = blockIdx.x;
  const int h  = bh & 7;
  const int qblk = blockIdx.y << 7;          // 0,128,256,384
  const int kblk = blockIdx.z << 6;          // 0..448 step 64
  const int tid = threadIdx.x;
  const int w = tid >> 6, lane = tid & 63;
  const int lo5 = lane & 31, hi = lane >> 5;
  const int wq = w << 5;                     // wave's q offset in tile (0/32/64/96)

  const float* Qg = Q + (size_t)bh * (SEQ * DK) + (size_t)qblk * DK;
  const float* Kg = K + (size_t)bh * (SEQ * DK) + (size_t)kblk * DK;

  // ---- stage tiles (fp32 -> bf16), coalesced ----
#pragma unroll
  for (int i = 0; i < 4; ++i) {              // Q: 128 rows x 8 chunks
    int f8 = i * 256 + tid;
    int row = f8 >> 3, c8 = f8 & 7;
    const float4* qp = (const float4*)(Qg + row * DK + c8 * 8);
    *(short8*)&Qs[row * LDSTRIDE + c8 * 8] = pack8(qp[0], qp[1]);
  }
#pragma unroll
  for (int i = 0; i < 2; ++i) {              // K: 64 rows x 8 chunks
    int f8 = i * 256 + tid;
    int row = f8 >> 3, c8 = f8 & 7;
    const float4* kp = (const float4*)(Kg + row * DK + c8 * 8);
    *(short8*)&Ks[row * LDSTRIDE + c8 * 8] = pack8(kp[0], kp[1]);
  }

  // ---- means A-fragment (rows 0..7 = cmin, 8..15 = cmax, 16..31 zero) ----
  const int cmin = (5 * h) >> 3;
  const int cmax = (5 * h + 4) >> 3;
  short8 mfrag[4];
#pragma unroll
  for (int s = 0; s < 4; ++s) {
    float4 a = {0.f, 0.f, 0.f, 0.f}, b = {0.f, 0.f, 0.f, 0.f};
    if (lo5 < 16) {
      int c = (lo5 < 8) ? cmin : cmax;
      const float* mp = means + c * 512 + (lo5 & 7) * 64 + s * 16 + hi * 8;
      a = *(const float4*)mp;
      b = *(const float4*)(mp + 4);
    }
    mfrag[s] = pack8(a, b);
  }

  __syncthreads();

  f32x16 zero;
#pragma unroll
  for (int x = 0; x < 16; ++x) zero[x] = 0.f;

  // ---- MFMA loop: 2 acc (k 0-31 / 32-63) + 1 qc per k-step ----
  f32x16 acc0 = zero, acc1 = zero, aq = zero;
#pragma unroll
  for (int s = 0; s < 4; ++s) {
    int co = s * 16 + hi * 8;
    short8 a  = *(const short8*)&Qs[(wq + lo5)  * LDSTRIDE + co];
    short8 b0 = *(const short8*)&Ks[lo5         * LDSTRIDE + co];
    short8 b1 = *(const short8*)&Ks[(32 + lo5)  * LDSTRIDE + co];
    acc0 = __builtin_amdgcn_mfma_f32_32x32x16_bf16(a, b0, acc0, 0, 0, 0);
    acc1 = __builtin_amdgcn_mfma_f32_32x32x16_bf16(a, b1, acc1, 0, 0, 0);
    aq   = __builtin_amdgcn_mfma_f32_32x32x16_bf16(mfrag[s], a, aq, 0, 0, 0);
  }

  // ---- in-lane qc extraction -> wave-private LDS (no barrier needed) ----
  {
    int qb = w * 320 + lo5 * 10 + 4 * hi;
    float2 p;
    p.x = fmaxf(aq[0], aq[4]) * 0.125f;
    p.y = fmaxf(aq[1], aq[5]) * 0.125f;
    *(float2*)&qcbuf[qb] = p;
    p.x = fmaxf(aq[2], aq[6]) * 0.125f;
    p.y = fmaxf(aq[3], aq[7]) * 0.125f;
    *(float2*)&qcbuf[qb + 2] = p;
  }

  // ---- epilogue: qc from LDS (same-wave), nontemporal streaming stores ----
  // k = kblk+lo5 and kblk+32+lo5 share (k&7) => same qc for both acc cols.
  float* ob = out + (size_t)bh * (SEQ * SEQ);
  const int kc0 = kblk + lo5;
  const int r = lo5 & 7;
  const int qcb = w * 320 + r;
#pragma unroll
  for (int g = 0; g < 4; ++g) {
#pragma unroll
    for (int e = 0; e < 4; ++e) {
      int reg = 4 * g + e;
      int ql = e + 8 * g + 4 * hi;           // q within wave's 32-row window
      float qc = qcbuf[qcb + ql * 10];
      int qrow = qblk + wq + ql;
      __builtin_nontemporal_store(fmaxf(acc0[reg] * 0.125f, qc),
                                  &ob[(size_t)qrow * SEQ + kc0]);
      __builtin_nontemporal_store(fmaxf(acc1[reg] * 0.125f, qc),
                                  &ob[(size_t)qrow * SEQ + kc0 + 32]);
    }
  }
}

extern "C" void kernel_launch(void* const* d_in, const int* in_sizes, int n_in,
                              void* d_out, int out_size, void* d_ws, size_t ws_size,
                              hipStream_t stream) {
  const float* Q  = (const float*)d_in[0];
  const float* K  = (const float*)d_in[1];
  const float* Wp = (const float*)d_in[2];
  const float* bp = (const float*)d_in[3];
  const float* Wq = (const float*)d_in[4];
  const float* bq = (const float*)d_in[5];
  const float* Wk = (const float*)d_in[6];
  const float* bk = (const float*)d_in[7];
  float* out = (float*)d_out;

  float* part  = (float*)d_ws;                     // 128*40 partials
  float* means = part + PROJ_BLOCKS * NB * NC;     // 5*512 floats
  float* loss_out = out + OUT_SCORE;

  void* args[] = {(void*)&K,  (void*)&Wp, (void*)&part, (void*)&bp,
                  (void*)&Wq, (void*)&bq, (void*)&Wk,   (void*)&bk,
                  (void*)&means, (void*)&loss_out};
  hipLaunchCooperativeKernel((const void*)proj_small_kernel,
                             dim3(PROJ_BLOCKS), dim3(256), args, 0, stream);

  dim3 grid(64, 4, 8);
  score_kernel<<<grid, 256, 0, stream>>>(Q, K, means, out);
}

// Round 2
// 137.982 us; speedup vs baseline: 1.2582x; 1.2582x over previous
//
#include <hip/hip_runtime.h>
#include <math.h>

#define NB 8
#define NH 8
#define SEQ 512
#define DK 64
#define NC 5
#define D_IN 262144   // 8*512*64 per batch
#define OUT_SCORE (NB*NH*SEQ*SEQ)   // 16777216
#define PROJ_BLOCKS 128

typedef short short8 __attribute__((ext_vector_type(8)));
typedef float f32x16 __attribute__((ext_vector_type(16)));

// fp32 -> bf16 (RTNE), bit pattern in a short
__device__ __forceinline__ short f2bf(float f) {
  unsigned u = __float_as_uint(f);
  u += 0x7fffu + ((u >> 16) & 1u);
  return (short)(u >> 16);
}
__device__ __forceinline__ short8 pack8(float4 a, float4 b) {
  short8 r;
  r[0] = f2bf(a.x); r[1] = f2bf(a.y); r[2] = f2bf(a.z); r[3] = f2bf(a.w);
  r[4] = f2bf(b.x); r[5] = f2bf(b.y); r[6] = f2bf(b.z); r[7] = f2bf(b.w);
  return r;
}

// ------- Kernel A: per-block partials of ck[b][c] (proven ~4 us) -------
__global__ __launch_bounds__(256) void proj_kernel(const float* __restrict__ K,
                                                   const float* __restrict__ Wp,
                                                   float* __restrict__ part) {
  const float4* Wp4 = (const float4*)Wp;
  float acc[NB][NC];
#pragma unroll
  for (int b = 0; b < NB; ++b)
#pragma unroll
    for (int c = 0; c < NC; ++c) acc[b][c] = 0.f;

#pragma unroll
  for (int it = 0; it < 2; ++it) {
    int i4 = blockIdx.x * 512 + it * 256 + threadIdx.x;  // float4 idx over D_IN
    float w[20];
#pragma unroll
    for (int t = 0; t < 5; ++t) {
      float4 v = Wp4[i4 * 5 + t];
      w[4*t+0] = v.x; w[4*t+1] = v.y; w[4*t+2] = v.z; w[4*t+3] = v.w;
    }
#pragma unroll
    for (int b = 0; b < NB; ++b) {
      float4 kv = ((const float4*)(K + (size_t)b * D_IN))[i4];
      float ke[4] = {kv.x, kv.y, kv.z, kv.w};
#pragma unroll
      for (int e = 0; e < 4; ++e)
#pragma unroll
        for (int c = 0; c < NC; ++c)
          acc[b][c] = fmaf(ke[e], w[5*e + c], acc[b][c]);
    }
  }

  __shared__ float red[4][NB * NC];
  int wave = threadIdx.x >> 6;
  int lane = threadIdx.x & 63;
#pragma unroll
  for (int bc = 0; bc < NB * NC; ++bc) {
    float v = acc[bc / NC][bc % NC];
#pragma unroll
    for (int off = 32; off > 0; off >>= 1) v += __shfl_down(v, off);
    if (lane == 0) red[wave][bc] = v;
  }
  __syncthreads();
  if (threadIdx.x < NB * NC)
    part[blockIdx.x * (NB * NC) + threadIdx.x] =
        red[0][threadIdx.x] + red[1][threadIdx.x] +
        red[2][threadIdx.x] + red[3][threadIdx.x];
}

// ---------------- Kernel B: reduce partials, stats, loss, means ----------
// colsum: 160 threads x 32-wide unrolled slices (32 independent loads in
// flight per thread) instead of the old 40-thread serial 128-deep chain.
__global__ __launch_bounds__(256) void small_kernel(
    const float* __restrict__ K, const float* __restrict__ part,
    const float* __restrict__ bp, const float* __restrict__ Wq,
    const float* __restrict__ bq, const float* __restrict__ Wk,
    const float* __restrict__ bk, float* __restrict__ means,
    float* __restrict__ loss_out) {
  __shared__ float cs4[4][NB * NC];
  __shared__ float colsum[NB * NC];
  __shared__ float cq[NB][NC], ckk[NB][NC], ce_sh[NB];
  __shared__ int inds[NB];
  int t = threadIdx.x;
  if (t < 160) {
    int sl = t / 40;
    int c  = t - sl * 40;
    float s = 0.f;
#pragma unroll
    for (int i = 0; i < 32; ++i) s += part[(sl * 32 + i) * (NB * NC) + c];
    cs4[sl][c] = s;
  }
  __syncthreads();
  if (t < NB * NC)
    colsum[t] = cs4[0][t] + cs4[1][t] + cs4[2][t] + cs4[3][t];
  __syncthreads();
  if (t < NB) {
    float cp[NC], zq[NC], zk[NC];
#pragma unroll
    for (int c = 0; c < NC; ++c) cp[c] = colsum[t * NC + c] + bp[c];
#pragma unroll
    for (int c = 0; c < NC; ++c) { zq[c] = bq[c]; zk[c] = bk[c]; }
#pragma unroll
    for (int j = 0; j < NC; ++j)
#pragma unroll
      for (int c = 0; c < NC; ++c) {
        zq[c] = fmaf(cp[j], Wq[j * NC + c], zq[c]);
        zk[c] = fmaf(cp[j], Wk[j * NC + c], zk[c]);
      }
    float m = zq[0];
#pragma unroll
    for (int c = 1; c < NC; ++c) m = fmaxf(m, zq[c]);
    float e[NC], s = 0.f;
#pragma unroll
    for (int c = 0; c < NC; ++c) { e[c] = expf(zq[c] - m); s += e[c]; }
    float inv = 1.f / s;
    float p[NC];
#pragma unroll
    for (int c = 0; c < NC; ++c) { p[c] = e[c] * inv; cq[t][c] = p[c]; }
    int am = 0; float bv = p[0];
#pragma unroll
    for (int c = 1; c < NC; ++c) if (p[c] > bv) { bv = p[c]; am = c; }
    inds[t] = am;
    float se = 0.f;
#pragma unroll
    for (int c = 0; c < NC; ++c) se += expf(p[c] - bv);
    float lse = bv + logf(se);
    float ceb = 0.f;
#pragma unroll
    for (int c = 0; c < NC; ++c) ceb -= p[c] * (p[c] - lse);
    ce_sh[t] = ceb;
    m = zk[0];
#pragma unroll
    for (int c = 1; c < NC; ++c) m = fmaxf(m, zk[c]);
    s = 0.f;
#pragma unroll
    for (int c = 0; c < NC; ++c) { e[c] = expf(zk[c] - m); s += e[c]; }
    inv = 1.f / s;
#pragma unroll
    for (int c = 0; c < NC; ++c) ckk[t][c] = e[c] * inv;
  }
  __syncthreads();
  if (t == 0) {
    float mu[NC];
#pragma unroll
    for (int c = 0; c < NC; ++c) {
      float sm = 0.f;
      for (int b = 0; b < NB; ++b) sm += cq[b][c];
      mu[c] = sm * 0.125f;
    }
    float loss_lp = 0.f;
#pragma unroll
    for (int c = 0; c < NC; ++c) {
      float sm = 0.f;
      for (int b = 0; b < NB; ++b) sm += ckk[b][c];
      float mk = sm * 0.125f;
      float var = 0.f;
      for (int b = 0; b < NB; ++b) {
        float d = ckk[b][c] - mk;
        var += d * d;
      }
      var *= (1.f / 7.f);                 // ddof=1
      float sd = sqrtf(var);
      float sigma = log1pf(expf(sd));     // softplus
      float ls = logf(sigma);
      for (int b = 0; b < NB; ++b) {
        float z = (ckk[b][c] - mu[c]) / sigma;
        loss_lp += -0.5f * z * z - ls - 0.91893853320467274f;
      }
    }
    float ce = 0.f;
    for (int b = 0; b < NB; ++b) ce += ce_sh[b];
    ce *= 0.125f;
    loss_out[0] = -(loss_lp / 40.f) + ce;
  }
  __syncthreads();
  // means[c][j] = (1/8) * sum_{b: inds[b] != c+1} K[b*D_IN + j],  j<512
  for (int idx = t; idx < NC * 512; idx += 256) {
    int c = idx >> 9, j = idx & 511;
    float sm = 0.f;
#pragma unroll
    for (int b = 0; b < NB; ++b)
      if (inds[b] != c + 1) sm += K[(size_t)b * D_IN + j];
    means[idx] = sm * 0.125f;
  }
}

// ---- Kernel C: 128q x 64k tiles, wave = 32q x 64k, 2048 blocks, 32 KB LDS ----
// L2-locality fix (T1): old grid had bh as the fastest blockIdx dim, so
// consecutive blocks (round-robin'd across the 8 XCDs) shared NOTHING and each
// XCD streamed all 16.8 MB of Q+K through its 4 MiB L2. New mapping: 1-D grid,
// XCD-chunked swizzle: blocks with bid%8==x form XCD x's contiguous chunk of
// 256 tiles = {8 bh} x {4 qblk} x {8 kblk}. Per-XCD working set = 1 MB K +
// 1 MB Q (L2-resident); Q tiles get 8x and K tiles 4x reuse out of L2.
// Output stores are nontemporal: 67 MB of streaming writes must not evict
// the L2-resident Q/K tiles.
#define LDSTRIDE 72   // shorts; 144 B rows: 16B-aligned, uniform b128 bank spread
__global__ __launch_bounds__(256) void score_kernel(const float* __restrict__ Q,
                                                    const float* __restrict__ K,
                                                    const float* __restrict__ means,
                                                    float* __restrict__ out) {
  __shared__ short Qs[128 * LDSTRIDE];       // 18432 B
  __shared__ short Ks[64 * LDSTRIDE];        //  9216 B
  __shared__ float qcbuf[4 * 32 * 10];       //  5120 B  => 32768 B total

  // XCD-chunked tile decode (2048 = 8 XCD x 256, bijective)
  const int swz = (blockIdx.x & 7) * 256 + (blockIdx.x >> 3);
  const int kblk = (swz & 7) << 6;           // fastest within chunk: 8 kblks
  const int grp  = swz >> 3;                 // 0..255
  const int qblk = (grp & 3) << 7;           // then 4 qblks
  const int bh   = grp >> 2;                 // 8 consecutive bh per XCD chunk
  const int h  = bh & 7;
  const int tid = threadIdx.x;
  const int w = tid >> 6, lane = tid & 63;
  const int lo5 = lane & 31, hi = lane >> 5;
  const int wq = w << 5;                     // wave's q offset in tile (0/32/64/96)

  const float* Qg = Q + (size_t)bh * (SEQ * DK) + (size_t)qblk * DK;
  const float* Kg = K + (size_t)bh * (SEQ * DK) + (size_t)kblk * DK;

  // ---- stage tiles (fp32 -> bf16), coalesced ----
#pragma unroll
  for (int i = 0; i < 4; ++i) {              // Q: 128 rows x 8 chunks
    int f8 = i * 256 + tid;
    int row = f8 >> 3, c8 = f8 & 7;
    const float4* qp = (const float4*)(Qg + row * DK + c8 * 8);
    *(short8*)&Qs[row * LDSTRIDE + c8 * 8] = pack8(qp[0], qp[1]);
  }
#pragma unroll
  for (int i = 0; i < 2; ++i) {              // K: 64 rows x 8 chunks
    int f8 = i * 256 + tid;
    int row = f8 >> 3, c8 = f8 & 7;
    const float4* kp = (const float4*)(Kg + row * DK + c8 * 8);
    *(short8*)&Ks[row * LDSTRIDE + c8 * 8] = pack8(kp[0], kp[1]);
  }

  // ---- means A-fragment (rows 0..7 = cmin, 8..15 = cmax, 16..31 zero) ----
  const int cmin = (5 * h) >> 3;
  const int cmax = (5 * h + 4) >> 3;
  short8 mfrag[4];
#pragma unroll
  for (int s = 0; s < 4; ++s) {
    float4 a = {0.f, 0.f, 0.f, 0.f}, b = {0.f, 0.f, 0.f, 0.f};
    if (lo5 < 16) {
      int c = (lo5 < 8) ? cmin : cmax;
      const float* mp = means + c * 512 + (lo5 & 7) * 64 + s * 16 + hi * 8;
      a = *(const float4*)mp;
      b = *(const float4*)(mp + 4);
    }
    mfrag[s] = pack8(a, b);
  }

  __syncthreads();

  f32x16 zero;
#pragma unroll
  for (int x = 0; x < 16; ++x) zero[x] = 0.f;

  // ---- MFMA loop: 2 acc (k 0-31 / 32-63) + 1 qc per k-step ----
  f32x16 acc0 = zero, acc1 = zero, aq = zero;
#pragma unroll
  for (int s = 0; s < 4; ++s) {
    int co = s * 16 + hi * 8;
    short8 a  = *(const short8*)&Qs[(wq + lo5)  * LDSTRIDE + co];
    short8 b0 = *(const short8*)&Ks[lo5         * LDSTRIDE + co];
    short8 b1 = *(const short8*)&Ks[(32 + lo5)  * LDSTRIDE + co];
    acc0 = __builtin_amdgcn_mfma_f32_32x32x16_bf16(a, b0, acc0, 0, 0, 0);
    acc1 = __builtin_amdgcn_mfma_f32_32x32x16_bf16(a, b1, acc1, 0, 0, 0);
    aq   = __builtin_amdgcn_mfma_f32_32x32x16_bf16(mfrag[s], a, aq, 0, 0, 0);
  }

  // ---- in-lane qc extraction -> wave-private LDS (no barrier needed) ----
  {
    int qb = w * 320 + lo5 * 10 + 4 * hi;
    float2 p;
    p.x = fmaxf(aq[0], aq[4]) * 0.125f;
    p.y = fmaxf(aq[1], aq[5]) * 0.125f;
    *(float2*)&qcbuf[qb] = p;
    p.x = fmaxf(aq[2], aq[6]) * 0.125f;
    p.y = fmaxf(aq[3], aq[7]) * 0.125f;
    *(float2*)&qcbuf[qb + 2] = p;
  }

  // ---- epilogue: qc from LDS (same-wave), nontemporal streaming stores ----
  // k = kblk+lo5 and kblk+32+lo5 share (k&7) => same qc for both acc cols.
  float* ob = out + (size_t)bh * (SEQ * SEQ);
  const int kc0 = kblk + lo5;
  const int r = lo5 & 7;
  const int qcb = w * 320 + r;
#pragma unroll
  for (int g = 0; g < 4; ++g) {
#pragma unroll
    for (int e = 0; e < 4; ++e) {
      int reg = 4 * g + e;
      int ql = e + 8 * g + 4 * hi;           // q within wave's 32-row window
      float qc = qcbuf[qcb + ql * 10];
      int qrow = qblk + wq + ql;
      __builtin_nontemporal_store(fmaxf(acc0[reg] * 0.125f, qc),
                                  &ob[(size_t)qrow * SEQ + kc0]);
      __builtin_nontemporal_store(fmaxf(acc1[reg] * 0.125f, qc),
                                  &ob[(size_t)qrow * SEQ + kc0 + 32]);
    }
  }
}

extern "C" void kernel_launch(void* const* d_in, const int* in_sizes, int n_in,
                              void* d_out, int out_size, void* d_ws, size_t ws_size,
                              hipStream_t stream) {
  const float* Q  = (const float*)d_in[0];
  const float* K  = (const float*)d_in[1];
  const float* Wp = (const float*)d_in[2];
  const float* bp = (const float*)d_in[3];
  const float* Wq = (const float*)d_in[4];
  const float* bq = (const float*)d_in[5];
  const float* Wk = (const float*)d_in[6];
  const float* bk = (const float*)d_in[7];
  float* out = (float*)d_out;

  float* part  = (float*)d_ws;                     // 128*40 partials
  float* means = part + PROJ_BLOCKS * NB * NC;     // 5*512 floats

  proj_kernel<<<PROJ_BLOCKS, 256, 0, stream>>>(K, Wp, part);
  small_kernel<<<1, 256, 0, stream>>>(K, part, bp, Wq, bq, Wk, bk, means,
                                      out + OUT_SCORE);
  score_kernel<<<2048, 256, 0, stream>>>(Q, K, means, out);
}

// Round 3
// 133.452 us; speedup vs baseline: 1.3009x; 1.0339x over previous
//
#include <hip/hip_runtime.h>
#include <math.h>

#define NB 8
#define NH 8
#define SEQ 512
#define DK 64
#define NC 5
#define D_IN 262144   // 8*512*64 per batch
#define OUT_SCORE (NB*NH*SEQ*SEQ)   // 16777216
#define PROJ_BLOCKS 128

typedef short short8 __attribute__((ext_vector_type(8)));
typedef float f32x16 __attribute__((ext_vector_type(16)));

// fp32 -> bf16 (RTNE), bit pattern in a short
__device__ __forceinline__ short f2bf(float f) {
  unsigned u = __float_as_uint(f);
  u += 0x7fffu + ((u >> 16) & 1u);
  return (short)(u >> 16);
}
__device__ __forceinline__ short8 pack8(float4 a, float4 b) {
  short8 r;
  r[0] = f2bf(a.x); r[1] = f2bf(a.y); r[2] = f2bf(a.z); r[3] = f2bf(a.w);
  r[4] = f2bf(b.x); r[5] = f2bf(b.y); r[6] = f2bf(b.z); r[7] = f2bf(b.w);
  return r;
}

// ------- Kernel A: per-block partials of ck[b][c] (proven ~4 us) -------
__global__ __launch_bounds__(256) void proj_kernel(const float* __restrict__ K,
                                                   const float* __restrict__ Wp,
                                                   float* __restrict__ part) {
  const float4* Wp4 = (const float4*)Wp;
  float acc[NB][NC];
#pragma unroll
  for (int b = 0; b < NB; ++b)
#pragma unroll
    for (int c = 0; c < NC; ++c) acc[b][c] = 0.f;

#pragma unroll
  for (int it = 0; it < 2; ++it) {
    int i4 = blockIdx.x * 512 + it * 256 + threadIdx.x;  // float4 idx over D_IN
    float w[20];
#pragma unroll
    for (int t = 0; t < 5; ++t) {
      float4 v = Wp4[i4 * 5 + t];
      w[4*t+0] = v.x; w[4*t+1] = v.y; w[4*t+2] = v.z; w[4*t+3] = v.w;
    }
#pragma unroll
    for (int b = 0; b < NB; ++b) {
      float4 kv = ((const float4*)(K + (size_t)b * D_IN))[i4];
      float ke[4] = {kv.x, kv.y, kv.z, kv.w};
#pragma unroll
      for (int e = 0; e < 4; ++e)
#pragma unroll
        for (int c = 0; c < NC; ++c)
          acc[b][c] = fmaf(ke[e], w[5*e + c], acc[b][c]);
    }
  }

  __shared__ float red[4][NB * NC];
  int wave = threadIdx.x >> 6;
  int lane = threadIdx.x & 63;
#pragma unroll
  for (int bc = 0; bc < NB * NC; ++bc) {
    float v = acc[bc / NC][bc % NC];
#pragma unroll
    for (int off = 32; off > 0; off >>= 1) v += __shfl_down(v, off);
    if (lane == 0) red[wave][bc] = v;
  }
  __syncthreads();
  if (threadIdx.x < NB * NC)
    part[blockIdx.x * (NB * NC) + threadIdx.x] =
        red[0][threadIdx.x] + red[1][threadIdx.x] +
        red[2][threadIdx.x] + red[3][threadIdx.x];
}

// ---- Kernel B (fused): redundant small-phase + 128q x 64k score tiles ----
// small_kernel is GONE: its output (means slice for this head's 2 clusters,
// inds, loss) is recomputed per block from `part` (20 KB, L2-resident) while
// the Q/K staging loads are in flight. Block 0 also writes the loss. LDS
// small-phase scratch + means union with qcbuf (barrier-separated phases),
// total LDS stays 32768 B -> 5 blocks/CU.
#define LDSTRIDE 72   // shorts; 144 B rows: 16B-aligned, uniform b128 bank spread
__global__ __launch_bounds__(256) void score_kernel(
    const float* __restrict__ Q, const float* __restrict__ K,
    const float* __restrict__ part, const float* __restrict__ bp,
    const float* __restrict__ Wq, const float* __restrict__ bq,
    const float* __restrict__ Wk, const float* __restrict__ bk,
    float* __restrict__ out) {
  __shared__ short Qs[128 * LDSTRIDE];       // 18432 B
  __shared__ short Ks[64 * LDSTRIDE];        //  9216 B
  __shared__ __align__(16) float sp[1280];   //  5120 B  => 32768 B total
  // sp union layout:
  //   phase S (small):  means_sh = sp[0..1023]  ([2][512])
  //                     inds     = (int*)&sp[1024] (8)
  //                     cs4      = &sp[1032] ([4][40], row0 doubles as colsum)
  //                     cq       = &sp[1192] ([8][5])
  //                     ckk      = &sp[1232] ([8][5])
  //                     ce       = &sp[1272] (8)
  //   phase E (epilogue): qcbuf = sp[0..1279]  (4 waves x 32 x 10)
  float* means_sh = sp;
  int*   inds_sh  = (int*)&sp[1024];
  float* cs4      = &sp[1032];
  float* cq_sh    = &sp[1192];
  float* ckk_sh   = &sp[1232];
  float* ce_sh    = &sp[1272];

  // XCD-chunked tile decode (2048 = 8 XCD x 256, bijective)
  const int swz = (blockIdx.x & 7) * 256 + (blockIdx.x >> 3);
  const int kblk = (swz & 7) << 6;           // fastest within chunk: 8 kblks
  const int grp  = swz >> 3;                 // 0..255
  const int qblk = (grp & 3) << 7;           // then 4 qblks
  const int bh   = grp >> 2;                 // 8 consecutive bh per XCD chunk
  const int h  = bh & 7;
  const int tid = threadIdx.x;
  const int w = tid >> 6, lane = tid & 63;
  const int lo5 = lane & 31, hi = lane >> 5;
  const int wq = w << 5;                     // wave's q offset in tile (0/32/64/96)

  const float* Qg = Q + (size_t)bh * (SEQ * DK) + (size_t)qblk * DK;
  const float* Kg = K + (size_t)bh * (SEQ * DK) + (size_t)kblk * DK;

  // ---- stage tiles FIRST (fp32 -> bf16): HBM loads issue before small-phase
#pragma unroll
  for (int i = 0; i < 4; ++i) {              // Q: 128 rows x 8 chunks
    int f8 = i * 256 + tid;
    int row = f8 >> 3, c8 = f8 & 7;
    const float4* qp = (const float4*)(Qg + row * DK + c8 * 8);
    *(short8*)&Qs[row * LDSTRIDE + c8 * 8] = pack8(qp[0], qp[1]);
  }
#pragma unroll
  for (int i = 0; i < 2; ++i) {              // K: 64 rows x 8 chunks
    int f8 = i * 256 + tid;
    int row = f8 >> 3, c8 = f8 & 7;
    const float4* kp = (const float4*)(Kg + row * DK + c8 * 8);
    *(short8*)&Ks[row * LDSTRIDE + c8 * 8] = pack8(kp[0], kp[1]);
  }

  // ---- small-phase: colsum of part (L2-warm) -> softmax -> inds/means ----
  if (tid < 160) {
    int sl = tid / 40, c = tid - sl * 40;
    float s = 0.f;
#pragma unroll
    for (int i = 0; i < 32; ++i) s += part[(sl * 32 + i) * (NB * NC) + c];
    cs4[sl * 40 + c] = s;
  }
  __syncthreads();
  if (tid < 40)
    cs4[tid] = cs4[tid] + cs4[40 + tid] + cs4[80 + tid] + cs4[120 + tid];
  __syncthreads();
  if (tid < NB) {
    float cp[NC], zq[NC], zk[NC];
#pragma unroll
    for (int c = 0; c < NC; ++c) cp[c] = cs4[tid * NC + c] + bp[c];
#pragma unroll
    for (int c = 0; c < NC; ++c) { zq[c] = bq[c]; zk[c] = bk[c]; }
#pragma unroll
    for (int j = 0; j < NC; ++j)
#pragma unroll
      for (int c = 0; c < NC; ++c) {
        zq[c] = fmaf(cp[j], Wq[j * NC + c], zq[c]);
        zk[c] = fmaf(cp[j], Wk[j * NC + c], zk[c]);
      }
    float m = zq[0];
#pragma unroll
    for (int c = 1; c < NC; ++c) m = fmaxf(m, zq[c]);
    float e[NC], s = 0.f;
#pragma unroll
    for (int c = 0; c < NC; ++c) { e[c] = expf(zq[c] - m); s += e[c]; }
    float inv = 1.f / s;
    float p[NC];
#pragma unroll
    for (int c = 0; c < NC; ++c) { p[c] = e[c] * inv; cq_sh[tid * NC + c] = p[c]; }
    int am = 0; float bv = p[0];
#pragma unroll
    for (int c = 1; c < NC; ++c) if (p[c] > bv) { bv = p[c]; am = c; }
    inds_sh[tid] = am;
    float se = 0.f;
#pragma unroll
    for (int c = 0; c < NC; ++c) se += expf(p[c] - bv);
    float lse = bv + logf(se);
    float ceb = 0.f;
#pragma unroll
    for (int c = 0; c < NC; ++c) ceb -= p[c] * (p[c] - lse);
    ce_sh[tid] = ceb;
    m = zk[0];
#pragma unroll
    for (int c = 1; c < NC; ++c) m = fmaxf(m, zk[c]);
    s = 0.f;
#pragma unroll
    for (int c = 0; c < NC; ++c) { e[c] = expf(zk[c] - m); s += e[c]; }
    inv = 1.f / s;
#pragma unroll
    for (int c = 0; c < NC; ++c) ckk_sh[tid * NC + c] = e[c] * inv;
  }
  __syncthreads();

  // ---- loss: block 0 thread 0 only (reads sp[1192..1279], no overlap with
  // means_sh writes at sp[0..1023] happening concurrently) ----
  if (blockIdx.x == 0 && tid == 0) {
    float mu[NC];
#pragma unroll
    for (int c = 0; c < NC; ++c) {
      float sm = 0.f;
      for (int b = 0; b < NB; ++b) sm += cq_sh[b * NC + c];
      mu[c] = sm * 0.125f;
    }
    float loss_lp = 0.f;
#pragma unroll
    for (int c = 0; c < NC; ++c) {
      float sm = 0.f;
      for (int b = 0; b < NB; ++b) sm += ckk_sh[b * NC + c];
      float mk = sm * 0.125f;
      float var = 0.f;
      for (int b = 0; b < NB; ++b) {
        float d = ckk_sh[b * NC + c] - mk;
        var += d * d;
      }
      var *= (1.f / 7.f);                 // ddof=1
      float sd = sqrtf(var);
      float sigma = log1pf(expf(sd));     // softplus
      float ls = logf(sigma);
      for (int b = 0; b < NB; ++b) {
        float z = (ckk_sh[b * NC + c] - mu[c]) / sigma;
        loss_lp += -0.5f * z * z - ls - 0.91893853320467274f;
      }
    }
    float ce = 0.f;
    for (int b = 0; b < NB; ++b) ce += ce_sh[b];
    ce *= 0.125f;
    out[OUT_SCORE] = -(loss_lp / 40.f) + ce;
  }

  // ---- means slice for this head's 2 clusters (K rows are L2/L3-hot) ----
  const int cmin = (5 * h) >> 3;
  const int cmax = (5 * h + 4) >> 3;
  for (int idx = tid; idx < 2 * 512; idx += 256) {
    int c2 = idx >> 9, j = idx & 511;
    int c = c2 ? cmax : cmin;
    float sm = 0.f;
#pragma unroll
    for (int b = 0; b < NB; ++b)
      if (inds_sh[b] != c + 1) sm += K[(size_t)b * D_IN + j];
    means_sh[idx] = sm * 0.125f;
  }
  __syncthreads();

  // ---- means A-fragment (rows 0..7 = cmin, 8..15 = cmax, 16..31 zero) ----
  short8 mfrag[4];
#pragma unroll
  for (int s = 0; s < 4; ++s) {
    float4 a = {0.f, 0.f, 0.f, 0.f}, b = {0.f, 0.f, 0.f, 0.f};
    if (lo5 < 16) {
      const float* mp = means_sh + (lo5 >> 3 << 9) + (lo5 & 7) * 64 + s * 16 + hi * 8;
      a = *(const float4*)mp;
      b = *(const float4*)(mp + 4);
    }
    mfrag[s] = pack8(a, b);
  }

  __syncthreads();   // mfrag/means reads done; qcbuf may now overwrite sp

  f32x16 zero;
#pragma unroll
  for (int x = 0; x < 16; ++x) zero[x] = 0.f;

  // ---- MFMA loop: 2 acc (k 0-31 / 32-63) + 1 qc per k-step ----
  f32x16 acc0 = zero, acc1 = zero, aq = zero;
#pragma unroll
  for (int s = 0; s < 4; ++s) {
    int co = s * 16 + hi * 8;
    short8 a  = *(const short8*)&Qs[(wq + lo5)  * LDSTRIDE + co];
    short8 b0 = *(const short8*)&Ks[lo5         * LDSTRIDE + co];
    short8 b1 = *(const short8*)&Ks[(32 + lo5)  * LDSTRIDE + co];
    acc0 = __builtin_amdgcn_mfma_f32_32x32x16_bf16(a, b0, acc0, 0, 0, 0);
    acc1 = __builtin_amdgcn_mfma_f32_32x32x16_bf16(a, b1, acc1, 0, 0, 0);
    aq   = __builtin_amdgcn_mfma_f32_32x32x16_bf16(mfrag[s], a, aq, 0, 0, 0);
  }

  // ---- in-lane qc extraction -> wave-private LDS (no barrier needed) ----
  float* qcbuf = sp;
  {
    int qb = w * 320 + lo5 * 10 + 4 * hi;
    float2 p;
    p.x = fmaxf(aq[0], aq[4]) * 0.125f;
    p.y = fmaxf(aq[1], aq[5]) * 0.125f;
    *(float2*)&qcbuf[qb] = p;
    p.x = fmaxf(aq[2], aq[6]) * 0.125f;
    p.y = fmaxf(aq[3], aq[7]) * 0.125f;
    *(float2*)&qcbuf[qb + 2] = p;
  }

  // ---- epilogue: qc from LDS (same-wave), nontemporal streaming stores ----
  // k = kblk+lo5 and kblk+32+lo5 share (k&7) => same qc for both acc cols.
  float* ob = out + (size_t)bh * (SEQ * SEQ);
  const int kc0 = kblk + lo5;
  const int r = lo5 & 7;
  const int qcb = w * 320 + r;
#pragma unroll
  for (int g = 0; g < 4; ++g) {
#pragma unroll
    for (int e = 0; e < 4; ++e) {
      int reg = 4 * g + e;
      int ql = e + 8 * g + 4 * hi;           // q within wave's 32-row window
      float qc = qcbuf[qcb + ql * 10];
      int qrow = qblk + wq + ql;
      __builtin_nontemporal_store(fmaxf(acc0[reg] * 0.125f, qc),
                                  &ob[(size_t)qrow * SEQ + kc0]);
      __builtin_nontemporal_store(fmaxf(acc1[reg] * 0.125f, qc),
                                  &ob[(size_t)qrow * SEQ + kc0 + 32]);
    }
  }
}

extern "C" void kernel_launch(void* const* d_in, const int* in_sizes, int n_in,
                              void* d_out, int out_size, void* d_ws, size_t ws_size,
                              hipStream_t stream) {
  const float* Q  = (const float*)d_in[0];
  const float* K  = (const float*)d_in[1];
  const float* Wp = (const float*)d_in[2];
  const float* bp = (const float*)d_in[3];
  const float* Wq = (const float*)d_in[4];
  const float* bq = (const float*)d_in[5];
  const float* Wk = (const float*)d_in[6];
  const float* bk = (const float*)d_in[7];
  float* out = (float*)d_out;

  float* part = (float*)d_ws;                      // 128*40 partials

  proj_kernel<<<PROJ_BLOCKS, 256, 0, stream>>>(K, Wp, part);
  score_kernel<<<2048, 256, 0, stream>>>(Q, K, part, bp, Wq, bq, Wk, bk, out);
}